// Round 9
// baseline (133.653 us; speedup 1.0000x reference)
//
#include <hip/hip_runtime.h>

// R19: perfect-packing 16-batch workgroup. B=4096, L=256, H=32, D=2.
// 256 WGs x 256 threads (4 waves), 16 batches/WG, 1 WG/CU, 1 wave/SIMD.
// Empirical law from R10-R18: step = per-SIMD issue + ~0.5-1.0x latency
// chain; no scheduling trick buys more hiding. So minimize issue+chain:
//  - B-tile cols = 16 DISTINCT batches (zero dup; R18 had 2x + 4x MFMA
//    redundancy). A-tile rows: row i of tile T = gate (i&3) of unit
//    8w + 2*(i>>2) + T -> lane (m,oct) acc[T][r] IS gate r of its cell
//    u(T) = 8w+2oct+T, batch m: zero extract ops, 2 MFMAs/wave = the
//    minimum (2048 gate-outputs). 2 cells/lane -> trans chain has ILP=2.
//  - bias+Wi*spin in MFMA C-in; every C slot is a used slot (no garbage).
//  - both h's pack to one ds_write_b32 (adjacent units 8w+2oct, +1).
//  - head logits: Wo-row MFMA round-robin by wave ((t-1)&3); S into Sbuf.
// Per-wave issue ~210cy (R18: ~380/SIMD); chain: bar -> ds_read 120 ->
// 2 indep MFMA -> 2-cell trans ~160 -> b32 write. Cell math (combined-rcp,
// 7 trans/cell), 4-step unroll + dword spin prefetch, post ELU/log-softmax
// carried from R18. Dynamic 44KB pad (if it registers: >80KB/WG -> 1 WG/CU
// guaranteed; else natural round-robin of grid 256 = CU count, R13 evidence).

typedef __attribute__((ext_vector_type(8))) short bf16x8;
typedef __attribute__((ext_vector_type(4))) float f32x4;

#define LOG2E 1.4426950408889634f
#define LN2   0.6931471805599453f

__device__ __forceinline__ float fexp2(float x) { return __builtin_amdgcn_exp2f(x); }
__device__ __forceinline__ float flog2(float x) { return __builtin_amdgcn_logf(x); }
__device__ __forceinline__ float frcp(float x)  { return __builtin_amdgcn_rcpf(x); }

__device__ __forceinline__ float fsig(float x)   { return frcp(1.f + fexp2(-LOG2E * x)); }
__device__ __forceinline__ float ftanh_(float x) { return 1.f - 2.f * frcp(fexp2(2.f * LOG2E * x) + 1.f); }
__device__ __forceinline__ float felu(float x)   { return x > 0.f ? x : fexp2(LOG2E * x) - 1.f; }

__device__ __forceinline__ unsigned short f2bf(float f) {   // RNE f32->bf16
    unsigned u = __builtin_bit_cast(unsigned, f);
    u = (u + 0x7FFFu + ((u >> 16) & 1u)) >> 16;
    return (unsigned short)u;
}

__device__ __forceinline__ unsigned cvtpk_bf16(float a, float b) {
    unsigned r;
    asm("v_cvt_pk_bf16_f32 %0, %1, %2" : "=v"(r) : "v"(a), "v"(b));
    return r;   // lo16 = bf16(a), hi16 = bf16(b), RNE
}

constexpr int Bsz = 4096;

__global__ __launch_bounds__(256, 1) void lstm_r19(
    const int*   __restrict__ x,    // [B, 256]
    const float* __restrict__ Wi,   // [2, 128]
    const float* __restrict__ Wh,   // [32, 128]
    const float* __restrict__ bh,   // [128]
    const float* __restrict__ Wo,   // [32, 2]
    const float* __restrict__ bo,   // [2]
    float*       __restrict__ out)  // [B]
{
    const int tid  = threadIdx.x;
    const int w    = tid >> 6;      // wave 0..3: owns units 8w..8w+7
    const int lane = tid & 63;
    const int m    = lane & 15;     // MFMA column == batch (16, no dup)
    const int oct  = lane >> 4;
    const int b0   = blockIdx.x * 16;

    extern __shared__ char dynpad[];      // occupancy cap (if it registers)
    __shared__ char   spinT[16][260];     // [batch][t] bytes, padded row
    __shared__ float2 Sbuf[256][16];      // raw logits (S0,S1) per (t,batch)
    __shared__ short  hbuf[2][16][40];    // h dbuf, row stride 80 B
    __shared__ float  red[16][16];
    if (blockIdx.x == 0xFFFFFFFFu) dynpad[0] = 1;

    // ---- stage spins: 256 threads x 16 bytes (16 rows x 256) ----
    {
        const int bl  = tid >> 4;          // row 0..15
        const int c16 = (tid & 15) * 16;   // 16 time-cols per thread
        const int4* src = reinterpret_cast<const int4*>(x + (b0 + bl) * 256 + c16);
#pragma unroll
        for (int q = 0; q < 4; ++q) {
            const int4 v = src[q];
            const int pk = (v.x & 1) | ((v.y & 1) << 8) | ((v.z & 1) << 16) | ((v.w & 1) << 24);
            *reinterpret_cast<int*>(&spinT[bl][c16 + 4 * q]) = pk;
        }
    }

    // ---- A-frags: tile T row i = gate (i&3) of unit 8w + 2*(i>>2) + T ----
    bf16x8 wfrag[2];
    {
        const int r = m & 3;
        const float gs = (r == 2) ? 2.f * LOG2E : -LOG2E;
#pragma unroll
        for (int T = 0; T < 2; ++T) {
            const int colg = 32 * r + 8 * w + 2 * (m >> 2) + T;
#pragma unroll
            for (int j = 0; j < 8; ++j)
                wfrag[T][j] = (short)f2bf(gs * Wh[(8 * oct + j) * 128 + colg]);
        }
    }
    bf16x8 wfragO;   // head: Wo cols in rows 0,1
#pragma unroll
    for (int j = 0; j < 8; ++j)
        wfragO[j] = (m < 2) ? (short)f2bf(Wo[(8 * oct + j) * 2 + m]) : (short)0;

    // ---- this lane's two cells + scaled biases ----
    const int uA = 8 * w + 2 * oct;      // even
    const int uB = uA + 1;
    float bv0A[4], bvdA[4], bv0B[4], bvdB[4];
#pragma unroll
    for (int r = 0; r < 4; ++r) {
        const float gs = (r == 2) ? 2.f * LOG2E : -LOG2E;
        const int cA = 32 * r + uA, cB = 32 * r + uB;
        bv0A[r] = gs * (bh[cA] + Wi[cA]); bvdA[r] = gs * (Wi[128 + cA] - Wi[cA]);
        bv0B[r] = gs * (bh[cB] + Wi[cB]); bvdB[r] = gs * (Wi[128 + cB] - Wi[cB]);
    }
    const float bo0 = bo[0], bo1 = bo[1];

    // ---- peel t=0: input zeros, h=c=0 -> gates = bh ----
    float cA = fsig(bh[uA]) * ftanh_(bh[64 + uA]);
    float cB = fsig(bh[uB]) * ftanh_(bh[64 + uB]);
    {
        const float hA = fsig(bh[96 + uA]) * ftanh_(cA);
        const float hB = fsig(bh[96 + uB]) * ftanh_(cB);
        *reinterpret_cast<int*>(&hbuf[0][m][uA]) = (int)cvtpk_bf16(hA, hB);
    }
    __syncthreads();   // spins + h0 visible

    const f32x4 zero4 = { 0.f, 0.f, 0.f, 0.f };

    auto cellup = [](const f32x4 a, float& cc) -> float {
        const float ei = fexp2(a[0]), ef = fexp2(a[1]);
        const float eg = fexp2(a[2]), eo = fexp2(a[3]);
        const float P = (1.f + ei) * (1.f + eg);
        const float Q = 1.f + ef;
        const float R = frcp(P * Q);
        cc = fmaf(P * R, cc, (eg - 1.f) * Q * R);   // sig(f)*c + sig(i)*tanh(g)
        const float ec = fexp2(2.f * LOG2E * cc);
        return (ec - 1.f) * frcp((1.f + eo) * (1.f + ec));   // sig(o)*tanh(c)
    };

    // one step; rb/wb/hw compile-time at each call site
    auto step = [&](const int t, const int rb, const int wb,
                    const float spf, const int hw) {
        const bf16x8 hfrag =
            *reinterpret_cast<const bf16x8*>(&hbuf[rb][m][8 * oct]);

        f32x4 cbA, cbB;   // per-slot-correct bias into MFMA C-in
#pragma unroll
        for (int r = 0; r < 4; ++r) {
            cbA[r] = fmaf(spf, bvdA[r], bv0A[r]);
            cbB[r] = fmaf(spf, bvdB[r], bv0B[r]);
        }

        const f32x4 accA = __builtin_amdgcn_mfma_f32_16x16x32_bf16(wfrag[0], hfrag, cbA, 0, 0, 0);
        const f32x4 accB = __builtin_amdgcn_mfma_f32_16x16x32_bf16(wfrag[1], hfrag, cbB, 0, 0, 0);

        // head logits of step t-1, round-robin wave (scalar branch)
        if (w == hw) {
            const f32x4 aO = __builtin_amdgcn_mfma_f32_16x16x32_bf16(wfragO, hfrag, zero4, 0, 0, 0);
            if (oct == 0) Sbuf[t - 1][m] = make_float2(aO[0], aO[1]);
        }

        // gates are DIRECTLY accA/accB (biased; zero extraction)
        const float hA = cellup(accA, cA);
        const float hB = cellup(accB, cB);
        *reinterpret_cast<int*>(&hbuf[wb][m][uA]) = (int)cvtpk_bf16(hA, hB);
        __syncthreads();
    };

    // 4-step unroll; spins for steps (tb..tb+3) = bytes (tb-1..tb+2), one
    // aligned dword. hw = (t-1)&3 is compile-time per slot.
    unsigned sp4 = *reinterpret_cast<const unsigned*>(&spinT[m][0]);
    for (int tb = 1; tb < 253; tb += 4) {
        const unsigned sp4n =
            *reinterpret_cast<const unsigned*>(&spinT[m][tb + 3]);
        step(tb,     0, 1, (float)(sp4 & 0xFFu),         0);
        step(tb + 1, 1, 0, (float)((sp4 >> 8) & 0xFFu),  1);
        step(tb + 2, 0, 1, (float)((sp4 >> 16) & 0xFFu), 2);
        step(tb + 3, 1, 0, (float)(sp4 >> 24),           3);
        sp4 = sp4n;
    }
    // tail steps 253..255 use spin bytes 252..254
    step(253, 0, 1, (float)(sp4 & 0xFFu),         0);
    step(254, 1, 0, (float)((sp4 >> 8) & 0xFFu),  1);
    step(255, 0, 1, (float)((sp4 >> 16) & 0xFFu), 2);

    // ---- tail: head logits of step 255 (h_255 in hbuf[1]) by wave 3 ----
    if (w == 3) {
        const bf16x8 hfrag = *reinterpret_cast<const bf16x8*>(&hbuf[1][m][8 * oct]);
        const f32x4 aO = __builtin_amdgcn_mfma_f32_16x16x32_bf16(wfragO, hfrag, zero4, 0, 0, 0);
        if (oct == 0) Sbuf[255][m] = make_float2(aO[0], aO[1]);
    }
    __syncthreads();

    // ---- post phase: ELU + log-softmax + sum over t, 16 time-chunks ----
    float lp = 0.f;
    {
        const int bpost = tid & 15;     // batch
        const int tc    = tid >> 4;     // time chunk 0..15
#pragma unroll
        for (int i = 0; i < 16; ++i) {
            const int t = tc * 16 + i;
            const float2 sv = Sbuf[t][bpost];
            const int sp = spinT[bpost][t];
            const float o0 = felu(sv.x + bo0);
            const float o1 = felu(sv.y + bo1);
            const float mx = fmaxf(o0, o1), mn = fminf(o0, o1);
            const float lse = mx + LN2 * flog2(1.f + fexp2(LOG2E * (mn - mx)));
            lp += (sp ? o1 : o0) - lse;
        }
        red[tc][bpost] = lp;
    }
    __syncthreads();
    if (tid < 16) {
        float s = 0.f;
#pragma unroll
        for (int tc2 = 0; tc2 < 16; ++tc2) s += red[tc2][tid];
        out[b0 + tid] = 0.5f * s;
    }
}

extern "C" void kernel_launch(void* const* d_in, const int* in_sizes, int n_in,
                              void* d_out, int out_size, void* d_ws, size_t ws_size,
                              hipStream_t stream) {
    const int*   x  = (const int*)d_in[0];
    const float* Wi = (const float*)d_in[1];
    const float* Wh = (const float*)d_in[2];
    const float* bh = (const float*)d_in[3];
    const float* Wo = (const float*)d_in[4];
    const float* bo = (const float*)d_in[5];
    float* out = (float*)d_out;

    // 256 WGs = 1 per CU (grid == CU count round-robins; dynamic 44KB pad
    // additionally forces 1 WG/CU if it registers: ~40.5K static + 44K > 80K).
    lstm_r19<<<dim3(Bsz / 16), dim3(256), 45056, stream>>>(x, Wi, Wh, bh, Wo, bo, out);
}

// Round 10
// 120.637 us; speedup vs baseline: 1.1079x; 1.1079x over previous
//
#include <hip/hip_runtime.h>

// R20: zero-dup 8-wave workgroup. B=4096, L=256, H=32, D=2.
// 256 WGs x 512 threads (8 waves), 16 batches/WG, 1 WG/CU, 2 waves/SIMD.
// Empirical law (R10-R19): step = issue/SIMD + unhidden_chain, where the
// chain term is ~360-435cy with 2 waves/SIMD and ~500+ with 1. R19 proved
// the zero-dup layout cuts issue as designed but ran 1 wave/SIMD; R20 keeps
// the layout and restores 2 waves/SIMD by spreading the 8 gate-tiles over
// 8 waves (R10's skeleton, minimum possible issue):
//  - tile T(=wave) row i = gate (i&3) of unit 4T+(i>>2); B-cols = 16
//    DISTINCT batches. Lane (m,oct) of wave T: acc[r] IS gate r of cell
//    u=4T+oct, batch m -> 1 MFMA/wave, zero extract, 1 cell/lane (7 trans
//    = per-lane floor), bias+Wi*spin in the MFMA C operand (every slot used).
//  - h: ds_write_b16 -> barrier -> ds_read_b128 (hbuf 80B-stride, proven).
//  - head logits: Wo-rows MFMA round-robin by (t-1)&7 (1/8 amortized).
// Cell math (combined-rcp, 7 trans), 4-step unroll + dword spin prefetch,
// cvt_pk h pack, post-loop ELU/log-softmax carried from R18/R19.

typedef __attribute__((ext_vector_type(8))) short bf16x8;
typedef __attribute__((ext_vector_type(4))) float f32x4;

#define LOG2E 1.4426950408889634f
#define LN2   0.6931471805599453f

__device__ __forceinline__ float fexp2(float x) { return __builtin_amdgcn_exp2f(x); }
__device__ __forceinline__ float flog2(float x) { return __builtin_amdgcn_logf(x); }
__device__ __forceinline__ float frcp(float x)  { return __builtin_amdgcn_rcpf(x); }

__device__ __forceinline__ float fsig(float x)   { return frcp(1.f + fexp2(-LOG2E * x)); }
__device__ __forceinline__ float ftanh_(float x) { return 1.f - 2.f * frcp(fexp2(2.f * LOG2E * x) + 1.f); }
__device__ __forceinline__ float felu(float x)   { return x > 0.f ? x : fexp2(LOG2E * x) - 1.f; }

__device__ __forceinline__ unsigned short f2bf(float f) {   // RNE f32->bf16
    unsigned u = __builtin_bit_cast(unsigned, f);
    u = (u + 0x7FFFu + ((u >> 16) & 1u)) >> 16;
    return (unsigned short)u;
}

__device__ __forceinline__ unsigned cvtpk_bf16(float a, float b) {
    unsigned r;
    asm("v_cvt_pk_bf16_f32 %0, %1, %2" : "=v"(r) : "v"(a), "v"(b));
    return r;   // lo16 = bf16(a), hi16 = bf16(b), RNE
}

constexpr int Bsz = 4096;

__global__ __launch_bounds__(512, 1) void lstm_r20(
    const int*   __restrict__ x,    // [B, 256]
    const float* __restrict__ Wi,   // [2, 128]
    const float* __restrict__ Wh,   // [32, 128]
    const float* __restrict__ bh,   // [128]
    const float* __restrict__ Wo,   // [32, 2]
    const float* __restrict__ bo,   // [2]
    float*       __restrict__ out)  // [B]
{
    const int tid  = threadIdx.x;
    const int w    = tid >> 6;      // wave 0..7 == gate tile
    const int lane = tid & 63;
    const int m    = lane & 15;     // MFMA column == batch (16, no dup)
    const int oct  = lane >> 4;
    const int b0   = blockIdx.x * 16;

    __shared__ char   spinT[16][260];     // [batch][t] bytes, padded row
    __shared__ float2 Sbuf[256][16];      // raw logits (S0,S1) per (t,batch)
    __shared__ short  hbuf[2][16][40];    // h dbuf, row stride 80 B
    __shared__ float  red[32][16];

    // ---- stage spins: 512 threads x 8 bytes (16 rows x 256) ----
    {
        const int bl = tid >> 5;          // row 0..15
        const int c8 = (tid & 31) * 8;
        const int4* src = reinterpret_cast<const int4*>(x + (b0 + bl) * 256 + c8);
        const int4 v0 = src[0], v1 = src[1];
        const int p0 = (v0.x & 1) | ((v0.y & 1) << 8) | ((v0.z & 1) << 16) | ((v0.w & 1) << 24);
        const int p1 = (v1.x & 1) | ((v1.y & 1) << 8) | ((v1.z & 1) << 16) | ((v1.w & 1) << 24);
        *reinterpret_cast<int*>(&spinT[bl][c8])     = p0;
        *reinterpret_cast<int*>(&spinT[bl][c8 + 4]) = p1;
    }

    // ---- A-frag: tile w, row m = gate (m&3) of unit 4w + (m>>2) ----
    bf16x8 wfrag;
    {
        const int r = m & 3;
        const float gs = (r == 2) ? 2.f * LOG2E : -LOG2E;
        const int colg = 32 * r + 4 * w + (m >> 2);
#pragma unroll
        for (int j = 0; j < 8; ++j)
            wfrag[j] = (short)f2bf(gs * Wh[(8 * oct + j) * 128 + colg]);
    }
    bf16x8 wfragO;   // head: Wo cols in rows 0,1
#pragma unroll
    for (int j = 0; j < 8; ++j)
        wfragO[j] = (m < 2) ? (short)f2bf(Wo[(8 * oct + j) * 2 + m]) : (short)0;

    // ---- this lane's cell + scaled biases ----
    const int u = 4 * w + oct;
    float bv0[4], bvd[4];
#pragma unroll
    for (int r = 0; r < 4; ++r) {
        const float gs = (r == 2) ? 2.f * LOG2E : -LOG2E;
        const int c0 = 32 * r + u;
        bv0[r] = gs * (bh[c0] + Wi[c0]);
        bvd[r] = gs * (Wi[128 + c0] - Wi[c0]);
    }
    const float bo0 = bo[0], bo1 = bo[1];

    // ---- peel t=0: input zeros, h=c=0 -> gates = bh ----
    float c = fsig(bh[u]) * ftanh_(bh[64 + u]);
    hbuf[0][m][u] = (short)f2bf(fsig(bh[96 + u]) * ftanh_(c));
    __syncthreads();   // spins + h0 visible

    const int wS = __builtin_amdgcn_readfirstlane(w);
    const f32x4 zero4 = { 0.f, 0.f, 0.f, 0.f };

    // one step; rb/wb compile-time at each call site -> static addresses
    auto step = [&](const int t, const int rb, const int wb, const float spf) {
        const bf16x8 hfrag =
            *reinterpret_cast<const bf16x8*>(&hbuf[rb][m][8 * oct]);

        f32x4 cb;   // bias into MFMA C-in; every slot is this lane's cell
#pragma unroll
        for (int r = 0; r < 4; ++r) cb[r] = fmaf(spf, bvd[r], bv0[r]);

        const f32x4 acc =
            __builtin_amdgcn_mfma_f32_16x16x32_bf16(wfrag, hfrag, cb, 0, 0, 0);

        // cell update (gates = acc directly); e_i=e^{-i}, e_f=e^{-f},
        // e_g=e^{2g}, e_o=e^{-o}; combined reciprocal saves one rcp.
        const float ei = fexp2(acc[0]), ef = fexp2(acc[1]);
        const float eg = fexp2(acc[2]), eo = fexp2(acc[3]);
        const float P = (1.f + ei) * (1.f + eg);
        const float Q = 1.f + ef;
        const float R = frcp(P * Q);
        c = fmaf(P * R, c, (eg - 1.f) * Q * R);   // sig(f)*c + sig(i)*tanh(g)
        const float ec = fexp2(2.f * LOG2E * c);
        const float h  = (ec - 1.f) * frcp((1.f + eo) * (1.f + ec));
        hbuf[wb][m][u] = (short)cvtpk_bf16(h, h);

        // head logits of step t-1: round-robin wave, off critical path
        if (wS == ((t - 1) & 7)) {
            const f32x4 aO =
                __builtin_amdgcn_mfma_f32_16x16x32_bf16(wfragO, hfrag, zero4, 0, 0, 0);
            if (oct == 0) Sbuf[t - 1][m] = make_float2(aO[0], aO[1]);
        }
        __syncthreads();   // h_t visible to all waves
    };

    // 4-step unroll; spins for steps (tb..tb+3) = bytes (tb-1..tb+2), one
    // aligned dword, prefetched a group ahead (tb-1 % 4 == 0 -> aligned).
    unsigned sp4 = *reinterpret_cast<const unsigned*>(&spinT[m][0]);
    for (int tb = 1; tb < 253; tb += 4) {
        const unsigned sp4n =
            *reinterpret_cast<const unsigned*>(&spinT[m][tb + 3]);
        step(tb,     0, 1, (float)(sp4 & 0xFFu));
        step(tb + 1, 1, 0, (float)((sp4 >> 8) & 0xFFu));
        step(tb + 2, 0, 1, (float)((sp4 >> 16) & 0xFFu));
        step(tb + 3, 1, 0, (float)(sp4 >> 24));
        sp4 = sp4n;
    }
    // tail steps 253..255 use spin bytes 252..254
    step(253, 0, 1, (float)(sp4 & 0xFFu));
    step(254, 1, 0, (float)((sp4 >> 8) & 0xFFu));
    step(255, 0, 1, (float)((sp4 >> 16) & 0xFFu));

    // ---- tail: head logits of step 255 (h_255 in hbuf[1]) by wave 7 ----
    if (wS == 7) {
        const bf16x8 hfrag = *reinterpret_cast<const bf16x8*>(&hbuf[1][m][8 * oct]);
        const f32x4 aO =
            __builtin_amdgcn_mfma_f32_16x16x32_bf16(wfragO, hfrag, zero4, 0, 0, 0);
        if (oct == 0) Sbuf[255][m] = make_float2(aO[0], aO[1]);
    }
    __syncthreads();

    // ---- post phase: ELU + log-softmax + sum over t, 32 time-chunks ----
    float lp = 0.f;
    {
        const int bpost = tid & 15;     // batch
        const int tc    = tid >> 4;     // time chunk 0..31
#pragma unroll
        for (int i = 0; i < 8; ++i) {
            const int t = tc * 8 + i;
            const float2 sv = Sbuf[t][bpost];
            const int sp = spinT[bpost][t];
            const float o0 = felu(sv.x + bo0);
            const float o1 = felu(sv.y + bo1);
            const float mx = fmaxf(o0, o1), mn = fminf(o0, o1);
            const float lse = mx + LN2 * flog2(1.f + fexp2(LOG2E * (mn - mx)));
            lp += (sp ? o1 : o0) - lse;
        }
        red[tc][bpost] = lp;
    }
    __syncthreads();
    if (tid < 16) {
        float s = 0.f;
#pragma unroll
        for (int tc2 = 0; tc2 < 32; ++tc2) s += red[tc2][tid];
        out[b0 + tid] = 0.5f * s;
    }
}

extern "C" void kernel_launch(void* const* d_in, const int* in_sizes, int n_in,
                              void* d_out, int out_size, void* d_ws, size_t ws_size,
                              hipStream_t stream) {
    const int*   x  = (const int*)d_in[0];
    const float* Wi = (const float*)d_in[1];
    const float* Wh = (const float*)d_in[2];
    const float* bh = (const float*)d_in[3];
    const float* Wo = (const float*)d_in[4];
    const float* bo = (const float*)d_in[5];
    float* out = (float*)d_out;

    // 256 WGs = 1 per CU; 8 waves/WG -> 2 waves per SIMD (same WG),
    // minimum-issue zero-dup layout.
    lstm_r20<<<dim3(Bsz / 16), dim3(512), 0, stream>>>(x, Wi, Wh, bh, Wo, bo, out);
}